// Round 6
// baseline (868.589 us; speedup 1.0000x reference)
//
#include <hip/hip_runtime.h>

// FAVOR+ attention, B=8 H=4 L=4096 D=128 M=640, fp32 in/out.
// out = (phi_q @ ctx) / (phi_q @ ksum); exp(eps)/sqrt(M) and per-row e^{-g_q}
// cancel in the ratio. Only g_k kept (fp16).
// R6: BARRIER-FREE main kernels. k1 waves split the m-chunk (not l) so the
// MFMA2 K-axis (l) is wave-local -> per-wave sPhiT slab, quad-shuffle ksum,
// no LDS sharing. k2 drops sCtx/sDred, computes D in-register (quad reduce),
// keeps wave-local sPhi round-trip; single barrier (sKs fill) per launch.

#define BH 32
#define LSEQ 4096
#define DIM 128
#define MFEAT 640
#define LDSW 136   // padded row stride (elements); 272 B rows

typedef __bf16 bf16x8 __attribute__((ext_vector_type(8)));
typedef float f32x4 __attribute__((ext_vector_type(4)));

__device__ __forceinline__ unsigned short f2b(float f) {
    union { float f; unsigned u; } c; c.f = f;
    unsigned u = c.u + 0x7FFFu + ((c.u >> 16) & 1u);   // RNE bf16 (finite inputs only)
    return (unsigned short)(u >> 16);
}
__device__ __forceinline__ float b2f(unsigned short h) {
    union { unsigned u; float f; } c; c.u = ((unsigned)h) << 16;
    return c.f;
}
__device__ __forceinline__ unsigned short f2h(float f) {
    union { _Float16 h; unsigned short u; } c; c.h = (_Float16)f; return c.u;
}
__device__ __forceinline__ float h2f(unsigned short u) {
    union { unsigned short u; _Float16 h; } c; c.u = u; return (float)c.h;
}
__device__ __forceinline__ bf16x8 ld8(const unsigned short* p) {
    union { uint4 q; bf16x8 v; } c;
    c.q = *reinterpret_cast<const uint4*>(p);
    return c.v;
}

// ---------------- prep: rows of 128, optional scale + g = 0.5*sum((x*s)^2) (fp16) -----------
__global__ void prep_rows(const float* __restrict__ src, unsigned short* __restrict__ dst,
                          unsigned short* __restrict__ gout, int nrows, float scale)
{
    const int row = blockIdx.x * 8 + (threadIdx.x >> 5);
    const int ln = threadIdx.x & 31;
    if (row >= nrows) return;
    const float4 f = *reinterpret_cast<const float4*>(src + (size_t)row * DIM + ln * 4);
    const float a = f.x * scale, b = f.y * scale, c = f.z * scale, d = f.w * scale;
    ushort4 o; o.x = f2b(a); o.y = f2b(b); o.z = f2b(c); o.w = f2b(d);
    *reinterpret_cast<ushort4*>(dst + (size_t)row * DIM + ln * 4) = o;
    if (gout != nullptr) {
        float ss = a * a + b * b + c * c + d * d;
        #pragma unroll
        for (int off = 16; off >= 1; off >>= 1) ss += __shfl_xor(ss, off, 64);
        if (ln == 0) gout[row] = f2h(0.5f * ss);
    }
}

// ---------------- prep: v [bh][l][e] fp32 -> vt [bh][e][l] bf16 ----------------
__global__ void prep_vt_k(const float* __restrict__ v, unsigned short* __restrict__ vt)
{
    __shared__ float tile[64][129];
    const int bh = blockIdx.x >> 6;
    const int l0 = (blockIdx.x & 63) * 64;
    const int tid = threadIdx.x;
    const float* vb = v + ((size_t)bh * LSEQ + l0) * DIM;
    for (int u = tid; u < 2048; u += 256) {
        const int r = u >> 5, c = (u & 31) * 4;
        const float4 f = *reinterpret_cast<const float4*>(vb + (size_t)r * DIM + c);
        tile[r][c] = f.x; tile[r][c + 1] = f.y; tile[r][c + 2] = f.z; tile[r][c + 3] = f.w;
    }
    __syncthreads();
    const int e = tid >> 1, hf = tid & 1;
    unsigned w[16];
    #pragma unroll
    for (int j = 0; j < 16; ++j) {
        w[j] = ((unsigned)f2b(tile[hf * 32 + 2 * j][e])) |
               (((unsigned)f2b(tile[hf * 32 + 2 * j + 1][e])) << 16);
    }
    unsigned short* dst = vt + ((size_t)bh * DIM + e) * LSEQ + l0 + hf * 32;
    uint4* d4 = reinterpret_cast<uint4*>(dst);
    d4[0] = make_uint4(w[0], w[1], w[2], w[3]);
    d4[1] = make_uint4(w[4], w[5], w[6], w[7]);
    d4[2] = make_uint4(w[8], w[9], w[10], w[11]);
    d4[3] = make_uint4(w[12], w[13], w[14], w[15]);
}

// ---------------- kernel 1: per-part ctx partials [part][bh][e][m] + ksum4 ----------------
// Waves split the 128-m chunk (32 m each). MFMA1: S[l=128][m=32/wave];
// MFMA2: ctx[m=32/wave][e=128] with K=l fully wave-local. ZERO barriers.
template<int MODE>
__global__ __launch_bounds__(256, 2) void k1_ctx(
    const unsigned short* __restrict__ kb, const unsigned short* __restrict__ gk,
    const unsigned short* __restrict__ projb, const unsigned short* __restrict__ vt,
    void* __restrict__ ctx4, float* __restrict__ ksum4)
{
    __shared__ __align__(16) unsigned short sPhiT[4][32 * LDSW];  // per-wave [m32][l128]

    const int tid = threadIdx.x;
    const int wave = tid >> 6, lane = tid & 63;
    const int quad = lane >> 4, lx = lane & 15;

    // XCD swizzle: same-bh blocks land on same XCD
    const int xcd = blockIdx.x & 7;
    const int kk = blockIdx.x >> 3;           // 0..79
    const int bh = xcd * 4 + kk / 20;
    const int t20 = kk % 20;
    const int part = t20 / 5;                 // L split 0..3
    const int mc = t20 % 5;                   // m-chunk 0..4 (128 each)
    const int mw0 = mc * 128 + wave * 32;     // wave's 32-m base
    const int lbase = part * 1024;

    f32x4 acc[2][8];
    #pragma unroll
    for (int i = 0; i < 2; ++i)
        #pragma unroll
        for (int j = 0; j < 8; ++j) acc[i][j] = f32x4{0.f, 0.f, 0.f, 0.f};
    float ksa0 = 0.f, ksa1 = 0.f;

    const unsigned short* kbase = kb + (size_t)bh * (LSEQ * DIM);
    const unsigned short* vbase = vt + (size_t)bh * (DIM * LSEQ);
    const unsigned short* gbase = gk + (size_t)bh * LSEQ;
    unsigned short* sP = sPhiT[wave];

    // wave's proj B-frags (loop-invariant, 32 VGPR)
    bf16x8 pb[2][4];
    #pragma unroll
    for (int mt = 0; mt < 2; ++mt)
        #pragma unroll
        for (int ks = 0; ks < 4; ++ks)
            pb[mt][ks] = ld8(projb + (size_t)(mw0 + mt * 16 + lx) * DIM + ks * 32 + quad * 8);

    #pragma unroll 1
    for (int tile = 0; tile < 8; ++tile) {
        const int l0 = lbase + tile * 128;

        #pragma unroll
        for (int half = 0; half < 2; ++half) {
            // MFMA1: S[ls 4][mt 2] covering l = l0 + half*64 .. +63, m = wave's 32
            f32x4 S[4][2];
            #pragma unroll
            for (int ls = 0; ls < 4; ++ls)
                #pragma unroll
                for (int mt = 0; mt < 2; ++mt) S[ls][mt] = f32x4{0.f, 0.f, 0.f, 0.f};
            #pragma unroll
            for (int ks = 0; ks < 4; ++ks)
                #pragma unroll
                for (int ls = 0; ls < 4; ++ls) {
                    const bf16x8 afr = ld8(kbase + (size_t)(l0 + (half * 4 + ls) * 16 + lx) * DIM + ks * 32 + quad * 8);
                    S[ls][0] = __builtin_amdgcn_mfma_f32_16x16x32_bf16(afr, pb[0][ks], S[ls][0], 0, 0, 0);
                    S[ls][1] = __builtin_amdgcn_mfma_f32_16x16x32_bf16(afr, pb[1][ks], S[ls][1], 0, 0, 0);
                }
            // exp(S - g) -> bf16 -> per-wave sPhiT [m][l]; ksum partials in regs
            #pragma unroll
            for (int ls = 0; ls < 4; ++ls) {
                const int lcol = (half * 4 + ls) * 16 + quad * 4;            // l-local 0..127
                const uint2 gu = *reinterpret_cast<const uint2*>(gbase + l0 + lcol);
                const float g0 = h2f((unsigned short)(gu.x & 0xffff));
                const float g1 = h2f((unsigned short)(gu.x >> 16));
                const float g2 = h2f((unsigned short)(gu.y & 0xffff));
                const float g3 = h2f((unsigned short)(gu.y >> 16));
                #pragma unroll
                for (int mt = 0; mt < 2; ++mt) {
                    ushort4 h;
                    h.x = f2b(__expf(S[ls][mt][0] - g0));
                    h.y = f2b(__expf(S[ls][mt][1] - g1));
                    h.z = f2b(__expf(S[ls][mt][2] - g2));
                    h.w = f2b(__expf(S[ls][mt][3] - g3));
                    const float sum4 = b2f(h.x) + b2f(h.y) + b2f(h.z) + b2f(h.w);
                    if (mt == 0) ksa0 += sum4; else ksa1 += sum4;
                    *reinterpret_cast<ushort4*>(&sP[(mt * 16 + lx) * LDSW + lcol]) = h;
                }
            }
        }
        // MFMA2: ctx[m 32][e 128] += phi^T . v, K = this tile's 128 l (wave-local)
        #pragma unroll
        for (int ks = 0; ks < 4; ++ks) {
            const bf16x8 pa0 = ld8(&sP[lx * LDSW + ks * 32 + quad * 8]);
            const bf16x8 pa1 = ld8(&sP[(16 + lx) * LDSW + ks * 32 + quad * 8]);
            #pragma unroll
            for (int et = 0; et < 8; ++et) {
                const bf16x8 vb = ld8(vbase + (size_t)(et * 16 + lx) * LSEQ + l0 + ks * 32 + quad * 8);
                acc[0][et] = __builtin_amdgcn_mfma_f32_16x16x32_bf16(pa0, vb, acc[0][et], 0, 0, 0);
                acc[1][et] = __builtin_amdgcn_mfma_f32_16x16x32_bf16(pa1, vb, acc[1][et], 0, 0, 0);
            }
        }
    }

    // transposed stores: ctx4[part][bh][e][m]; lane holds 4 consecutive m (r)
    #pragma unroll
    for (int mt = 0; mt < 2; ++mt)
        #pragma unroll
        for (int et = 0; et < 8; ++et) {
            const size_t off = (((size_t)part * BH + bh) * DIM + et * 16 + lx) * MFEAT
                             + mw0 + mt * 16 + quad * 4;
            if (MODE == 0) {
                float4 st; st.x = acc[mt][et][0]; st.y = acc[mt][et][1];
                st.z = acc[mt][et][2]; st.w = acc[mt][et][3];
                *reinterpret_cast<float4*>((float*)ctx4 + off) = st;
            } else {
                ushort4 st; st.x = f2b(acc[mt][et][0]); st.y = f2b(acc[mt][et][1]);
                st.z = f2b(acc[mt][et][2]); st.w = f2b(acc[mt][et][3]);
                *reinterpret_cast<ushort4*>((unsigned short*)ctx4 + off) = st;
            }
        }
    // ksum: reduce over quads (l-partition) -> wave-local store
    ksa0 += __shfl_xor(ksa0, 16, 64); ksa0 += __shfl_xor(ksa0, 32, 64);
    ksa1 += __shfl_xor(ksa1, 16, 64); ksa1 += __shfl_xor(ksa1, 32, 64);
    if (quad == 0) {
        ksum4[((size_t)part * BH + bh) * MFEAT + mw0 + lx] = ksa0;
        ksum4[((size_t)part * BH + bh) * MFEAT + mw0 + 16 + lx] = ksa1;
    }
}

// ---------------- cvt: sum 4 partials -> ctxb bf16 [bh][e][m] (elementwise) ----------------
#define PELEM (size_t)(BH * DIM * MFEAT)   // 2,621,440 per partial
template<int MODE>
__global__ void k_cvt(const float* __restrict__ pf, const unsigned short* __restrict__ ph,
                      unsigned short* __restrict__ ctxb)
{
    const size_t base = ((size_t)blockIdx.x * 256 + threadIdx.x) * 4;
    float s0, s1, s2, s3;
    if (MODE == 0) {
        float4 a = *reinterpret_cast<const float4*>(pf + base);
        float4 b = *reinterpret_cast<const float4*>(pf + PELEM + base);
        float4 c = *reinterpret_cast<const float4*>(pf + 2 * PELEM + base);
        float4 d = *reinterpret_cast<const float4*>(pf + 3 * PELEM + base);
        s0 = a.x + b.x + c.x + d.x; s1 = a.y + b.y + c.y + d.y;
        s2 = a.z + b.z + c.z + d.z; s3 = a.w + b.w + c.w + d.w;
    } else {
        ushort4 a = *reinterpret_cast<const ushort4*>(ph + base);
        ushort4 b = *reinterpret_cast<const ushort4*>(ph + PELEM + base);
        ushort4 c = *reinterpret_cast<const ushort4*>(ph + 2 * PELEM + base);
        ushort4 d = *reinterpret_cast<const ushort4*>(ph + 3 * PELEM + base);
        s0 = b2f(a.x) + b2f(b.x) + b2f(c.x) + b2f(d.x);
        s1 = b2f(a.y) + b2f(b.y) + b2f(c.y) + b2f(d.y);
        s2 = b2f(a.z) + b2f(b.z) + b2f(c.z) + b2f(d.z);
        s3 = b2f(a.w) + b2f(b.w) + b2f(c.w) + b2f(d.w);
    }
    ushort4 o; o.x = f2b(s0); o.y = f2b(s1); o.z = f2b(s2); o.w = f2b(s3);
    *reinterpret_cast<ushort4*>(ctxb + base) = o;   // MODE 1: in-place over partial 0 (own slot)
}

// ---------------- kernel 2: out = (phi_q @ ctx) / (phi_q @ ksum) ----------------
// 128-row tiles, grid 1024, XCD swizzle. Wave-local sPhi round-trip, D in
// registers (quad reduce + shfl broadcast). ONE barrier total (sKs fill).
__global__ __launch_bounds__(256, 3) void k2_out(
    const float* __restrict__ q, const unsigned short* __restrict__ projb,
    const unsigned short* __restrict__ ctxb, const float* __restrict__ ksum4,
    float* __restrict__ out, float scale)
{
    __shared__ __align__(16) unsigned short sPhi[128 * LDSW];   // [l][m], wave-private rows
    __shared__ float sKs[MFEAT];

    const int tid = threadIdx.x;
    const int wave = tid >> 6, lane = tid & 63;
    const int quad = lane >> 4, lx = lane & 15;

    // XCD swizzle: 32 blocks per bh share one XCD (ctxb[bh] stays L2-hot)
    const int xcd = blockIdx.x & 7;
    const int kk = blockIdx.x >> 3;           // 0..127
    const int bh = xcd * 4 + (kk >> 5);
    const int l0 = (kk & 31) * 128;

    for (int i = tid; i < MFEAT; i += 256)
        sKs[i] = ksum4[(size_t)bh * MFEAT + i]
               + ksum4[(size_t)(BH + bh) * MFEAT + i]
               + ksum4[(size_t)(2 * BH + bh) * MFEAT + i]
               + ksum4[(size_t)(3 * BH + bh) * MFEAT + i];

    // q frags: fp32 -> scaled bf16 in-reg (32 VGPR), B-operand of swapped MFMA1
    bf16x8 qa[2][4];
    #pragma unroll
    for (int lt = 0; lt < 2; ++lt)
        #pragma unroll
        for (int ks = 0; ks < 4; ++ks) {
            const float* p = q + ((size_t)bh * LSEQ + l0 + wave * 32 + lt * 16 + lx) * DIM + ks * 32 + quad * 8;
            const float4 f0 = *reinterpret_cast<const float4*>(p);
            const float4 f1 = *reinterpret_cast<const float4*>(p + 4);
            union { unsigned u[4]; bf16x8 v; } c;
            c.u[0] = ((unsigned)f2b(f0.x * scale)) | (((unsigned)f2b(f0.y * scale)) << 16);
            c.u[1] = ((unsigned)f2b(f0.z * scale)) | (((unsigned)f2b(f0.w * scale)) << 16);
            c.u[2] = ((unsigned)f2b(f1.x * scale)) | (((unsigned)f2b(f1.y * scale)) << 16);
            c.u[3] = ((unsigned)f2b(f1.z * scale)) | (((unsigned)f2b(f1.w * scale)) << 16);
            qa[lt][ks] = c.v;
        }

    f32x4 oacc[2][8];
    #pragma unroll
    for (int i = 0; i < 2; ++i)
        #pragma unroll
        for (int j = 0; j < 8; ++j) oacc[i][j] = f32x4{0.f, 0.f, 0.f, 0.f};
    float dacc0 = 0.f, dacc1 = 0.f;

    __syncthreads();   // sKs ready — the ONLY barrier in this kernel

    #pragma unroll 1
    for (int c5 = 0; c5 < 5; ++c5) {
        const int m0 = c5 * 128;

        // swapped MFMA1: S'[m, l] = proj . q^T ; 8 chains per lt; packed writes
        // to the wave's OWN sPhi rows; D-partial accumulated in regs.
        #pragma unroll
        for (int lt = 0; lt < 2; ++lt) {
            f32x4 S[8];
            #pragma unroll
            for (int mt = 0; mt < 8; ++mt) S[mt] = f32x4{0.f, 0.f, 0.f, 0.f};
            #pragma unroll
            for (int ks = 0; ks < 4; ++ks)
                #pragma unroll
                for (int mt = 0; mt < 8; ++mt) {
                    const bf16x8 pa = ld8(projb + (size_t)(m0 + mt * 16 + lx) * DIM + ks * 32 + quad * 8);
                    S[mt] = __builtin_amdgcn_mfma_f32_16x16x32_bf16(pa, qa[lt][ks], S[mt], 0, 0, 0);
                }
            float dl = 0.f;
            #pragma unroll
            for (int mt = 0; mt < 8; ++mt) {
                ushort4 h;
                h.x = f2b(__expf(S[mt][0])); h.y = f2b(__expf(S[mt][1]));
                h.z = f2b(__expf(S[mt][2])); h.w = f2b(__expf(S[mt][3]));
                const float4 kv = *reinterpret_cast<const float4*>(&sKs[m0 + mt * 16 + quad * 4]);
                dl += b2f(h.x) * kv.x + b2f(h.y) * kv.y + b2f(h.z) * kv.z + b2f(h.w) * kv.w;
                *reinterpret_cast<ushort4*>(&sPhi[(wave * 32 + lt * 16 + lx) * LDSW + mt * 16 + quad * 4]) = h;
            }
            if (lt == 0) dacc0 += dl; else dacc1 += dl;
        }
        // MFMA2: out[l(32/wave), e(128)] += phi_q . ctx ; wave-local sPhi reads,
        // ctxb B-frags from global (L2-hot). No barrier.
        #pragma unroll
        for (int ks = 0; ks < 4; ++ks) {
            const bf16x8 pa0 = ld8(&sPhi[(wave * 32 + lx) * LDSW + ks * 32 + quad * 8]);
            const bf16x8 pa1 = ld8(&sPhi[(wave * 32 + 16 + lx) * LDSW + ks * 32 + quad * 8]);
            #pragma unroll
            for (int et = 0; et < 8; ++et) {
                const bf16x8 cb = ld8(ctxb + ((size_t)bh * DIM + et * 16 + lx) * MFEAT + m0 + ks * 32 + quad * 8);
                oacc[0][et] = __builtin_amdgcn_mfma_f32_16x16x32_bf16(pa0, cb, oacc[0][et], 0, 0, 0);
                oacc[1][et] = __builtin_amdgcn_mfma_f32_16x16x32_bf16(pa1, cb, oacc[1][et], 0, 0, 0);
            }
        }
    }

    // D: reduce over quads (each quad held 32 of the 128 m per chunk), then
    // broadcast D[l = wave*32 + lt*16 + quad*4 + r] from lane (quad*4+r).
    dacc0 += __shfl_xor(dacc0, 16, 64); dacc0 += __shfl_xor(dacc0, 32, 64);
    dacc1 += __shfl_xor(dacc1, 16, 64); dacc1 += __shfl_xor(dacc1, 32, 64);
    #pragma unroll
    for (int lt = 0; lt < 2; ++lt)
        #pragma unroll
        for (int r = 0; r < 4; ++r) {
            const float Dv = __shfl(lt ? dacc1 : dacc0, quad * 4 + r, 64);
            const float inv = 1.0f / Dv;
            const int lrow = wave * 32 + lt * 16 + quad * 4 + r;
            float* ob = out + ((size_t)bh * LSEQ + l0 + lrow) * DIM;
            #pragma unroll
            for (int et = 0; et < 8; ++et)
                ob[et * 16 + lx] = oacc[lt][et][r] * inv;
        }
}

extern "C" void kernel_launch(void* const* d_in, const int* in_sizes, int n_in,
                              void* d_out, int out_size, void* d_ws, size_t ws_size,
                              hipStream_t stream)
{
    (void)in_sizes; (void)n_in; (void)out_size;
    const float* q = (const float*)d_in[0];
    const float* k = (const float*)d_in[1];
    const float* v = (const float*)d_in[2];
    const float* proj = (const float*)d_in[3];
    float* out = (float*)d_out;
    char* ws = (char*)d_ws;

    // ws layout (bytes):
    //   kb     @ 0          33,554,432
    //   vt     @ 33,554,432 33,554,432   (dead after k1; ctxb aliases here in MODE 0)
    //   projb  @ 67,108,864    163,840
    //   gk     @ 67,272,704    262,144   (fp16)
    //   ksum4  @ 67,534,848    327,680
    //   ctx4   @ 67,862,528  41,943,040 fp32 (MODE 0) | 20,971,520 bf16 (MODE 1, ctxb in-place)
    unsigned short* kb    = (unsigned short*)(ws);
    unsigned short* vt    = (unsigned short*)(ws + 33554432);
    unsigned short* projb = (unsigned short*)(ws + 67108864);
    unsigned short* gk    = (unsigned short*)(ws + 67272704);
    float*          ksum4 = (float*)         (ws + 67534848);
    char*           ctx4  = ws + 67862528;

    const bool modeA = (ws_size >= 109805568u);   // fp32 partials fit?
    unsigned short* ctxb = modeA ? (unsigned short*)(ws + 33554432)   // alias over dead vt
                                 : (unsigned short*)ctx4;             // in-place over partial 0

    const float s = 0.2973017787506803f;  // 1/128^0.25

    prep_rows<<<16384, 256, 0, stream>>>(k, kb, gk, BH * LSEQ, s);
    prep_rows<<<80, 256, 0, stream>>>(proj, projb, nullptr, MFEAT, 1.0f);
    prep_vt_k<<<BH * 64, 256, 0, stream>>>(v, vt);
    if (modeA) {
        k1_ctx<0><<<640, 256, 0, stream>>>(kb, gk, projb, vt, ctx4, ksum4);
        k_cvt<0><<<2560, 256, 0, stream>>>((const float*)ctx4, nullptr, ctxb);
    } else {
        k1_ctx<1><<<640, 256, 0, stream>>>(kb, gk, projb, vt, ctx4, ksum4);
        k_cvt<1><<<2560, 256, 0, stream>>>(nullptr, (const unsigned short*)ctx4, ctxb);
    }
    k2_out<<<1024, 256, 0, stream>>>(q, projb, ctxb, ksum4, out, s);
}